// Round 1
// baseline (1548.857 us; speedup 1.0000x reference)
//
#include <hip/hip_runtime.h>
#include <stdint.h>

#define N_NODES   50000
#define N_EDGES   800000
#define IN_DIM    128
#define OUT_DIM   128
#define NUM_RELS  8
#define TILE_E    32
#define THREADS   256

// sorted edge-id array is padded so every tile is single-relation
#define SORT_N    (N_EDGES + NUM_RELS * TILE_E)   // 800256
#define N_TILES   (SORT_N / TILE_E)               // 25008

// ws layout: [0,32) counts[8] | [32,64) cursors[8] | [64, 64+SORT_N*4) sorted ids
#define WS_NEEDED (64 + (size_t)SORT_N * 4)

__device__ __forceinline__ unsigned short f2bf(float x) {
    unsigned u = __float_as_uint(x);
    unsigned r = (u + 0x7FFFu + ((u >> 16) & 1u)) >> 16;   // round-to-nearest-even
    return (unsigned short)r;
}
__device__ __forceinline__ float bf2f(unsigned short b) {
    return __uint_as_float(((unsigned)b) << 16);
}

// ---- pass 1: per-relation histogram (block-local LDS hist, 8 global atomics/block)
__global__ void hist_kernel(const int* __restrict__ rel, int* __restrict__ counts) {
    __shared__ int lc[NUM_RELS];
    int t = threadIdx.x;
    if (t < NUM_RELS) lc[t] = 0;
    __syncthreads();
    int i = blockIdx.x * blockDim.x + t;
    if (i < N_EDGES) atomicAdd(&lc[rel[i]], 1);
    __syncthreads();
    if (t < NUM_RELS && lc[t]) atomicAdd(&counts[t], lc[t]);
}

// ---- pass 2: tile-padded exclusive prefix over 8 counts
__global__ void scan_kernel(const int* __restrict__ counts, int* __restrict__ cursors) {
    if (threadIdx.x == 0 && blockIdx.x == 0) {
        int off = 0;
        for (int r = 0; r < NUM_RELS; r++) {
            cursors[r] = off;
            int c = counts[r];
            off += ((c + TILE_E - 1) / TILE_E) * TILE_E;
        }
    }
}

// ---- pass 3: scatter edge ids into relation-sorted order
__global__ void scatter_kernel(const int* __restrict__ rel, int* __restrict__ cursors,
                               int* __restrict__ sorted) {
    __shared__ int lc[NUM_RELS];
    __shared__ int base[NUM_RELS];
    int t = threadIdx.x;
    if (t < NUM_RELS) lc[t] = 0;
    __syncthreads();
    int i = blockIdx.x * blockDim.x + t;
    int r = 0, lo = 0;
    if (i < N_EDGES) { r = rel[i]; lo = atomicAdd(&lc[r], 1); }
    __syncthreads();
    if (t < NUM_RELS) base[t] = lc[t] ? atomicAdd(&cursors[t], lc[t]) : 0;
    __syncthreads();
    if (i < N_EDGES) sorted[base[r] + lo] = i;
}

// ---- pass 4: per-tile GEMM-ish compute + atomic scatter
__global__ __launch_bounds__(THREADS) void compute_kernel(
    const float* __restrict__ feat, const float* __restrict__ rel_emb,
    const float* __restrict__ ew, const int* __restrict__ src,
    const int* __restrict__ dst, const int* __restrict__ rel,
    const int* __restrict__ sorted, float* __restrict__ out)
{
    __shared__ unsigned short Wt[IN_DIM][OUT_DIM];   // bf16 bits, 32 KB
    __shared__ float Ft[TILE_E][IN_DIM];             // weighted src feats, 16 KB
    __shared__ int   Dt[TILE_E];
    __shared__ int   St[TILE_E];
    __shared__ float Wg[TILE_E];
    __shared__ int   Rt;

    const int t = threadIdx.x;
    const int tile0 = blockIdx.x * TILE_E;

    // edge metadata; sentinel id (-1) => weight 0, node 0 (contributes nothing)
    if (t < TILE_E) {
        int id = sorted[tile0 + t];
        float w = 0.f; int s = 0, d = -1;
        if (id >= 0) { w = ew[id]; s = src[id]; d = dst[id]; }
        St[t] = s; Wg[t] = w; Dt[t] = d;
        if (t == 0) Rt = (id >= 0) ? rel[id] : 0;
    }
    __syncthreads();

    // stage W[Rt] as bf16 (float4 loads, ushort4 stores)
    {
        const float4* Wsrc = (const float4*)(rel_emb + (size_t)Rt * IN_DIM * OUT_DIM);
        ushort4* Wdst = (ushort4*)&Wt[0][0];
        for (int i = t; i < IN_DIM * OUT_DIM / 4; i += THREADS) {
            float4 v = Wsrc[i];
            ushort4 o;
            o.x = f2bf(v.x); o.y = f2bf(v.y); o.z = f2bf(v.z); o.w = f2bf(v.w);
            Wdst[i] = o;
        }
    }
    // stage gathered, weight-scaled features (8 edges per pass)
    for (int p = 0; p < TILE_E; p += 8) {
        int e = p + (t >> 5);
        int c = (t & 31) * 4;
        float4 v = *(const float4*)(feat + (size_t)St[e] * IN_DIM + c);
        float w = Wg[e];
        v.x *= w; v.y *= w; v.z *= w; v.w *= w;
        *(float4*)&Ft[e][c] = v;
    }
    __syncthreads();

    // register tile: 4 edges x 4 out-cols per thread
    const int jq = t & 31, eq = t >> 5;
    const int j0 = jq * 4, e0 = eq * 4;
    float acc[4][4] = {};
    for (int k = 0; k < IN_DIM; k += 4) {
        float4 fa[4];
        #pragma unroll
        for (int i = 0; i < 4; i++) fa[i] = *(const float4*)&Ft[e0 + i][k];
        #pragma unroll
        for (int kk = 0; kk < 4; kk++) {
            ushort4 wb = *(const ushort4*)&Wt[k + kk][j0];
            float w0 = bf2f(wb.x), w1 = bf2f(wb.y), w2 = bf2f(wb.z), w3 = bf2f(wb.w);
            #pragma unroll
            for (int i = 0; i < 4; i++) {
                float fv = ((const float*)&fa[i])[kk];
                acc[i][0] += fv * w0;
                acc[i][1] += fv * w1;
                acc[i][2] += fv * w2;
                acc[i][3] += fv * w3;
            }
        }
    }

    // scatter-add to destination nodes
    #pragma unroll
    for (int i = 0; i < 4; i++) {
        int d = Dt[e0 + i];
        if (d >= 0) {
            float* op = out + (size_t)d * OUT_DIM + j0;
            atomicAdd(op + 0, acc[i][0]);
            atomicAdd(op + 1, acc[i][1]);
            atomicAdd(op + 2, acc[i][2]);
            atomicAdd(op + 3, acc[i][3]);
        }
    }
}

// ---- fallback (no workspace): wave-per-edge direct
__global__ void naive_kernel(const float* __restrict__ feat, const float* __restrict__ rel_emb,
                             const float* __restrict__ ew, const int* __restrict__ src,
                             const int* __restrict__ dst, const int* __restrict__ rel,
                             float* __restrict__ out) {
    int wave = (blockIdx.x * blockDim.x + threadIdx.x) >> 6;
    int lane = threadIdx.x & 63;
    if (wave >= N_EDGES) return;
    const float* f = feat + (size_t)src[wave] * IN_DIM;
    const float* W = rel_emb + (size_t)rel[wave] * IN_DIM * OUT_DIM;
    float w = ew[wave];
    float a0 = 0.f, a1 = 0.f;
    for (int k = 0; k < IN_DIM; k++) {
        float fv = f[k];
        a0 += fv * W[k * OUT_DIM + lane];
        a1 += fv * W[k * OUT_DIM + 64 + lane];
    }
    int d = dst[wave];
    atomicAdd(&out[(size_t)d * OUT_DIM + lane], a0 * w);
    atomicAdd(&out[(size_t)d * OUT_DIM + 64 + lane], a1 * w);
}

extern "C" void kernel_launch(void* const* d_in, const int* in_sizes, int n_in,
                              void* d_out, int out_size, void* d_ws, size_t ws_size,
                              hipStream_t stream) {
    const float* feat    = (const float*)d_in[0];
    const float* rel_emb = (const float*)d_in[1];
    const float* ew      = (const float*)d_in[2];
    const int*   src     = (const int*)d_in[3];
    const int*   dst     = (const int*)d_in[4];
    const int*   rel     = (const int*)d_in[5];
    float* out = (float*)d_out;

    hipMemsetAsync(d_out, 0, (size_t)out_size * sizeof(float), stream);

    if (ws_size >= WS_NEEDED) {
        int* counts  = (int*)d_ws;
        int* cursors = counts + 8;
        int* sorted  = (int*)((char*)d_ws + 64);

        hipMemsetAsync(d_ws, 0, 64, stream);                       // counts+cursors
        hipMemsetAsync(sorted, 0xFF, (size_t)SORT_N * 4, stream);  // -1 sentinels

        const int eb = (N_EDGES + THREADS - 1) / THREADS;          // 3125
        hist_kernel<<<eb, THREADS, 0, stream>>>(rel, counts);
        scan_kernel<<<1, 64, 0, stream>>>(counts, cursors);
        scatter_kernel<<<eb, THREADS, 0, stream>>>(rel, cursors, sorted);
        compute_kernel<<<N_TILES, THREADS, 0, stream>>>(feat, rel_emb, ew, src, dst, rel,
                                                        sorted, out);
    } else {
        const long long total = (long long)N_EDGES * 64;
        const int blocks = (int)((total + THREADS - 1) / THREADS);
        naive_kernel<<<blocks, THREADS, 0, stream>>>(feat, rel_emb, ew, src, dst, rel, out);
    }
}

// Round 2
// 391.165 us; speedup vs baseline: 3.9596x; 3.9596x over previous
//
#include <hip/hip_runtime.h>
#include <stdint.h>

#define N_NODES   50000
#define N_EDGES   800000
#define IN_DIM    128
#define OUT_DIM   128
#define NUM_RELS  8
#define THREADS   256

typedef _Float16 half_t;
typedef _Float16 half8 __attribute__((ext_vector_type(8)));
typedef _Float16 half2v __attribute__((ext_vector_type(2)));
typedef float floatx4 __attribute__((ext_vector_type(4)));

// ===================== NEW PATH: sort by (dst,rel) -> segmented sum -> dense MFMA GEMM =====================
// key = dst*8 + rel, NBINS bins; h[d][r][k] = sum_{e->d,rel=r} w_e * feat[src_e][k]  (f16)
// out[d][n] = sum_{r,k} h[d][r][k] * W[r][k][n]  == GEMM  [50000 x 1024] @ [1024 x 128]
#define NBINS     (N_NODES * NUM_RELS)            // 400000
#define NB        ((NBINS + 1023) / 1024)         // 391 scan blocks (256 thr x 4 elems)

// ws layout (bytes)
#define WS_CURS   0                               // cursors / hist  : NBINS i32 (aliased)
#define WS_OFF    1600000                         // off             : NBINS+1 i32
#define WS_BSUM   3200016                         // block sums/offs : NB i32
#define WS_SORT   3201584                         // sorted edge ids : N_EDGES i32
#define WS_WT     6401584                         // W^T f16         : 128 x 1024
#define WS_H      6663728                         // h f16           : 50000 x 1024
#define WS2_NEEDED (6663728 + (size_t)N_NODES * 1024 * 2)   // 109,063,728

__global__ void hist2_kernel(const int* __restrict__ dst, const int* __restrict__ rel,
                             int* __restrict__ hist) {
    int i = blockIdx.x * blockDim.x + threadIdx.x;
    if (i < N_EDGES) atomicAdd(&hist[dst[i] * NUM_RELS + rel[i]], 1);
}

__global__ void scan1_kernel(const int* __restrict__ hist, int* __restrict__ bsum) {
    __shared__ int sh[256];
    int b = blockIdx.x, t = threadIdx.x;
    int i0 = b * 1024 + t * 4;
    int s = 0;
    #pragma unroll
    for (int j = 0; j < 4; j++) { int idx = i0 + j; if (idx < NBINS) s += hist[idx]; }
    sh[t] = s; __syncthreads();
    for (int o = 128; o > 0; o >>= 1) { if (t < o) sh[t] += sh[t + o]; __syncthreads(); }
    if (t == 0) bsum[b] = sh[0];
}

__global__ void scan2_kernel(int* __restrict__ bsum, int* __restrict__ off) {
    if (threadIdx.x == 0 && blockIdx.x == 0) {
        int run = 0;
        for (int b = 0; b < NB; b++) { int c = bsum[b]; bsum[b] = run; run += c; }
        off[NBINS] = N_EDGES;
    }
}

__global__ void scan3_kernel(const int* __restrict__ hist, const int* __restrict__ boff,
                             int* __restrict__ off, int* __restrict__ cursors) {
    __shared__ int sh[256];
    int b = blockIdx.x, t = threadIdx.x;
    int i0 = b * 1024 + t * 4;
    int v[4]; int s = 0;
    #pragma unroll
    for (int j = 0; j < 4; j++) { int idx = i0 + j; v[j] = (idx < NBINS) ? hist[idx] : 0; s += v[j]; }
    sh[t] = s; __syncthreads();
    for (int o = 1; o < 256; o <<= 1) {
        int x = (t >= o) ? sh[t - o] : 0;
        __syncthreads();
        sh[t] += x;
        __syncthreads();
    }
    int run = sh[t] - s + boff[b];
    #pragma unroll
    for (int j = 0; j < 4; j++) {
        int idx = i0 + j;
        if (idx < NBINS) { off[idx] = run; cursors[idx] = run; }
        run += v[j];
    }
}

__global__ void scatter2_kernel(const int* __restrict__ dst, const int* __restrict__ rel,
                                int* __restrict__ cursors, int* __restrict__ sorted) {
    int i = blockIdx.x * blockDim.x + threadIdx.x;
    if (i < N_EDGES) {
        int key = dst[i] * NUM_RELS + rel[i];
        int pos = atomicAdd(&cursors[key], 1);
        sorted[pos] = i;
    }
}

// rel_emb flat [1024 kk][128 n] fp32  ->  WT [128 n][1024 kk] f16
__global__ void prep_wt_kernel(const float* __restrict__ rel_emb, half_t* __restrict__ WT) {
    int t = blockIdx.x * blockDim.x + threadIdx.x;
    if (t < 1024 * 128) {
        int kk = t & 1023, n = t >> 10;
        WT[(size_t)n * 1024 + kk] = (half_t)rel_emb[(size_t)kk * 128 + n];
    }
}

// one wave per (dst,rel) group: h[g][0:128] = sum_e w_e * feat[src_e]
__global__ __launch_bounds__(THREADS) void phaseA_kernel(
    const float* __restrict__ feat, const float* __restrict__ ew,
    const int* __restrict__ src, const int* __restrict__ sorted,
    const int* __restrict__ off, half_t* __restrict__ h) {
    int g = blockIdx.x * 4 + (threadIdx.x >> 6);
    int lane = threadIdx.x & 63;
    int beg = off[g], end = off[g + 1];
    float ax = 0.f, ay = 0.f;
    for (int e = beg; e < end; e++) {
        int id = sorted[e];
        float w = ew[id];
        const float2 v = *(const float2*)(feat + (size_t)src[id] * IN_DIM + lane * 2);
        ax += w * v.x; ay += w * v.y;
    }
    half2v o; o[0] = (half_t)ax; o[1] = (half_t)ay;
    *(half2v*)(h + (size_t)g * 128 + lane * 2) = o;
}

// out[50000 x 128] = h[50000 x 1024] @ WT^T, f16 MFMA, 128-row tiles
#define GM_TILE 128
#define GBK     64
#define APAD    72   // row stride in halfs (64 + 8 pad -> 2-way-free bank pattern)
__global__ __launch_bounds__(THREADS) void gemm_kernel(
    const half_t* __restrict__ h, const half_t* __restrict__ WT,
    float* __restrict__ out) {
    __shared__ half_t As[GM_TILE][APAD];   // 18.4 KB
    __shared__ half_t Bs[128][APAD];       // 18.4 KB
    const int t = threadIdx.x;
    const int wave = t >> 6, lane = t & 63;
    const int q = lane >> 4, l16 = lane & 15;
    const int m0 = blockIdx.x * GM_TILE;

    floatx4 acc[2][8];
    #pragma unroll
    for (int i = 0; i < 2; i++)
        #pragma unroll
        for (int j = 0; j < 8; j++) acc[i][j] = (floatx4){0.f, 0.f, 0.f, 0.f};

    const int rt = t >> 3;          // 0..31
    const int kp = (t & 7) * 8;     // 0..56

    for (int kc = 0; kc < 1024; kc += GBK) {
        __syncthreads();
        #pragma unroll
        for (int p = 0; p < 4; p++) {
            int r = p * 32 + rt;
            int row = m0 + r;
            uint4 v = {0u, 0u, 0u, 0u};
            if (row < N_NODES) v = *(const uint4*)(h + (size_t)row * 1024 + kc + kp);
            *(uint4*)&As[r][kp] = v;
            uint4 w = *(const uint4*)(WT + (size_t)r * 1024 + kc + kp);
            *(uint4*)&Bs[r][kp] = w;
        }
        __syncthreads();
        #pragma unroll
        for (int ks = 0; ks < GBK; ks += 32) {
            half8 a0 = *(const half8*)&As[wave * 32 + l16][ks + q * 8];
            half8 a1 = *(const half8*)&As[wave * 32 + 16 + l16][ks + q * 8];
            #pragma unroll
            for (int nt = 0; nt < 8; nt++) {
                half8 b = *(const half8*)&Bs[nt * 16 + l16][ks + q * 8];
                acc[0][nt] = __builtin_amdgcn_mfma_f32_16x16x32_f16(a0, b, acc[0][nt], 0, 0, 0);
                acc[1][nt] = __builtin_amdgcn_mfma_f32_16x16x32_f16(a1, b, acc[1][nt], 0, 0, 0);
            }
        }
    }
    // C/D layout: col = l16, row = q*4 + reg
    #pragma unroll
    for (int rg = 0; rg < 2; rg++)
        #pragma unroll
        for (int nt = 0; nt < 8; nt++)
            #pragma unroll
            for (int reg = 0; reg < 4; reg++) {
                int row = m0 + wave * 32 + rg * 16 + q * 4 + reg;
                if (row < N_NODES) out[(size_t)row * 128 + nt * 16 + l16] = acc[rg][nt][reg];
            }
}

// ===================== OLD PATH (round-1, ws fallback): rel-sorted tiles + atomics =====================
#define TILE_E    32
#define SORT_N    (N_EDGES + NUM_RELS * TILE_E)
#define N_TILES   (SORT_N / TILE_E)
#define WS1_NEEDED (64 + (size_t)SORT_N * 4)

__device__ __forceinline__ unsigned short f2bf(float x) {
    unsigned u = __float_as_uint(x);
    unsigned r = (u + 0x7FFFu + ((u >> 16) & 1u)) >> 16;
    return (unsigned short)r;
}
__device__ __forceinline__ float bf2f(unsigned short b) {
    return __uint_as_float(((unsigned)b) << 16);
}

__global__ void hist_kernel(const int* __restrict__ rel, int* __restrict__ counts) {
    __shared__ int lc[NUM_RELS];
    int t = threadIdx.x;
    if (t < NUM_RELS) lc[t] = 0;
    __syncthreads();
    int i = blockIdx.x * blockDim.x + t;
    if (i < N_EDGES) atomicAdd(&lc[rel[i]], 1);
    __syncthreads();
    if (t < NUM_RELS && lc[t]) atomicAdd(&counts[t], lc[t]);
}

__global__ void scan_kernel(const int* __restrict__ counts, int* __restrict__ cursors) {
    if (threadIdx.x == 0 && blockIdx.x == 0) {
        int off = 0;
        for (int r = 0; r < NUM_RELS; r++) {
            cursors[r] = off;
            off += ((counts[r] + TILE_E - 1) / TILE_E) * TILE_E;
        }
    }
}

__global__ void scatter_kernel(const int* __restrict__ rel, int* __restrict__ cursors,
                               int* __restrict__ sorted) {
    __shared__ int lc[NUM_RELS];
    __shared__ int base[NUM_RELS];
    int t = threadIdx.x;
    if (t < NUM_RELS) lc[t] = 0;
    __syncthreads();
    int i = blockIdx.x * blockDim.x + t;
    int r = 0, lo = 0;
    if (i < N_EDGES) { r = rel[i]; lo = atomicAdd(&lc[r], 1); }
    __syncthreads();
    if (t < NUM_RELS) base[t] = lc[t] ? atomicAdd(&cursors[t], lc[t]) : 0;
    __syncthreads();
    if (i < N_EDGES) sorted[base[r] + lo] = i;
}

__global__ __launch_bounds__(THREADS) void compute_kernel(
    const float* __restrict__ feat, const float* __restrict__ rel_emb,
    const float* __restrict__ ew, const int* __restrict__ src,
    const int* __restrict__ dst, const int* __restrict__ rel,
    const int* __restrict__ sorted, float* __restrict__ out) {
    __shared__ unsigned short Wt[IN_DIM][OUT_DIM];
    __shared__ float Ft[TILE_E][IN_DIM];
    __shared__ int   Dt[TILE_E];
    __shared__ int   St[TILE_E];
    __shared__ float Wg[TILE_E];
    __shared__ int   Rt;
    const int t = threadIdx.x;
    const int tile0 = blockIdx.x * TILE_E;
    if (t < TILE_E) {
        int id = sorted[tile0 + t];
        float w = 0.f; int s = 0, d = -1;
        if (id >= 0) { w = ew[id]; s = src[id]; d = dst[id]; }
        St[t] = s; Wg[t] = w; Dt[t] = d;
        if (t == 0) Rt = (id >= 0) ? rel[id] : 0;
    }
    __syncthreads();
    {
        const float4* Wsrc = (const float4*)(rel_emb + (size_t)Rt * IN_DIM * OUT_DIM);
        ushort4* Wdst = (ushort4*)&Wt[0][0];
        for (int i = t; i < IN_DIM * OUT_DIM / 4; i += THREADS) {
            float4 v = Wsrc[i];
            ushort4 o;
            o.x = f2bf(v.x); o.y = f2bf(v.y); o.z = f2bf(v.z); o.w = f2bf(v.w);
            Wdst[i] = o;
        }
    }
    for (int p = 0; p < TILE_E; p += 8) {
        int e = p + (t >> 5);
        int c = (t & 31) * 4;
        float4 v = *(const float4*)(feat + (size_t)St[e] * IN_DIM + c);
        float w = Wg[e];
        v.x *= w; v.y *= w; v.z *= w; v.w *= w;
        *(float4*)&Ft[e][c] = v;
    }
    __syncthreads();
    const int jq = t & 31, eq = t >> 5;
    const int j0 = jq * 4, e0 = eq * 4;
    float acc[4][4] = {};
    for (int k = 0; k < IN_DIM; k += 4) {
        float4 fa[4];
        #pragma unroll
        for (int i = 0; i < 4; i++) fa[i] = *(const float4*)&Ft[e0 + i][k];
        #pragma unroll
        for (int kk = 0; kk < 4; kk++) {
            ushort4 wb = *(const ushort4*)&Wt[k + kk][j0];
            float w0 = bf2f(wb.x), w1 = bf2f(wb.y), w2 = bf2f(wb.z), w3 = bf2f(wb.w);
            #pragma unroll
            for (int i = 0; i < 4; i++) {
                float fv = ((const float*)&fa[i])[kk];
                acc[i][0] += fv * w0;
                acc[i][1] += fv * w1;
                acc[i][2] += fv * w2;
                acc[i][3] += fv * w3;
            }
        }
    }
    #pragma unroll
    for (int i = 0; i < 4; i++) {
        int d = Dt[e0 + i];
        if (d >= 0) {
            float* op = out + (size_t)d * OUT_DIM + j0;
            atomicAdd(op + 0, acc[i][0]);
            atomicAdd(op + 1, acc[i][1]);
            atomicAdd(op + 2, acc[i][2]);
            atomicAdd(op + 3, acc[i][3]);
        }
    }
}

__global__ void naive_kernel(const float* __restrict__ feat, const float* __restrict__ rel_emb,
                             const float* __restrict__ ew, const int* __restrict__ src,
                             const int* __restrict__ dst, const int* __restrict__ rel,
                             float* __restrict__ out) {
    int wave = (blockIdx.x * blockDim.x + threadIdx.x) >> 6;
    int lane = threadIdx.x & 63;
    if (wave >= N_EDGES) return;
    const float* f = feat + (size_t)src[wave] * IN_DIM;
    const float* W = rel_emb + (size_t)rel[wave] * IN_DIM * OUT_DIM;
    float w = ew[wave];
    float a0 = 0.f, a1 = 0.f;
    for (int k = 0; k < IN_DIM; k++) {
        float fv = f[k];
        a0 += fv * W[k * OUT_DIM + lane];
        a1 += fv * W[k * OUT_DIM + 64 + lane];
    }
    int d = dst[wave];
    atomicAdd(&out[(size_t)d * OUT_DIM + lane], a0 * w);
    atomicAdd(&out[(size_t)d * OUT_DIM + 64 + lane], a1 * w);
}

extern "C" void kernel_launch(void* const* d_in, const int* in_sizes, int n_in,
                              void* d_out, int out_size, void* d_ws, size_t ws_size,
                              hipStream_t stream) {
    const float* feat    = (const float*)d_in[0];
    const float* rel_emb = (const float*)d_in[1];
    const float* ew      = (const float*)d_in[2];
    const int*   src     = (const int*)d_in[3];
    const int*   dst     = (const int*)d_in[4];
    const int*   rel     = (const int*)d_in[5];
    float* out = (float*)d_out;

    const int eb = (N_EDGES + THREADS - 1) / THREADS;   // 3125

    if (ws_size >= WS2_NEEDED) {
        char* ws = (char*)d_ws;
        int*    cursors = (int*)(ws + WS_CURS);    // also the histogram
        int*    off     = (int*)(ws + WS_OFF);
        int*    bsum    = (int*)(ws + WS_BSUM);
        int*    sorted  = (int*)(ws + WS_SORT);
        half_t* WT      = (half_t*)(ws + WS_WT);
        half_t* h       = (half_t*)(ws + WS_H);

        hipMemsetAsync(cursors, 0, (size_t)NBINS * 4, stream);
        hist2_kernel<<<eb, THREADS, 0, stream>>>(dst, rel, cursors);
        scan1_kernel<<<NB, 256, 0, stream>>>(cursors, bsum);
        scan2_kernel<<<1, 64, 0, stream>>>(bsum, off);
        scan3_kernel<<<NB, 256, 0, stream>>>(cursors, bsum, off, cursors);
        scatter2_kernel<<<eb, THREADS, 0, stream>>>(dst, rel, cursors, sorted);
        prep_wt_kernel<<<(1024 * 128 + THREADS - 1) / THREADS, THREADS, 0, stream>>>(rel_emb, WT);
        phaseA_kernel<<<NBINS / 4, THREADS, 0, stream>>>(feat, ew, src, sorted, off, h);
        gemm_kernel<<<(N_NODES + GM_TILE - 1) / GM_TILE, THREADS, 0, stream>>>(h, WT, out);
    } else if (ws_size >= WS1_NEEDED) {
        hipMemsetAsync(d_out, 0, (size_t)out_size * sizeof(float), stream);
        int* counts  = (int*)d_ws;
        int* cursors = counts + 8;
        int* sorted  = (int*)((char*)d_ws + 64);
        hipMemsetAsync(d_ws, 0, 64, stream);
        hipMemsetAsync(sorted, 0xFF, (size_t)SORT_N * 4, stream);
        hist_kernel<<<eb, THREADS, 0, stream>>>(rel, counts);
        scan_kernel<<<1, 64, 0, stream>>>(counts, cursors);
        scatter_kernel<<<eb, THREADS, 0, stream>>>(rel, cursors, sorted);
        compute_kernel<<<N_TILES, THREADS, 0, stream>>>(feat, rel_emb, ew, src, dst, rel,
                                                        sorted, out);
    } else {
        hipMemsetAsync(d_out, 0, (size_t)out_size * sizeof(float), stream);
        const long long total = (long long)N_EDGES * 64;
        const int blocks = (int)((total + THREADS - 1) / THREADS);
        naive_kernel<<<blocks, THREADS, 0, stream>>>(feat, rel_emb, ew, src, dst, rel, out);
    }
}

// Round 3
// 300.375 us; speedup vs baseline: 5.1564x; 1.3023x over previous
//
#include <hip/hip_runtime.h>
#include <stdint.h>

#define N_NODES   50000
#define N_EDGES   800000
#define IN_DIM    128
#define OUT_DIM   128
#define NUM_RELS  8
#define THREADS   256

typedef _Float16 half_t;
typedef _Float16 half2v __attribute__((ext_vector_type(2)));
typedef _Float16 half4v __attribute__((ext_vector_type(4)));
typedef _Float16 half8 __attribute__((ext_vector_type(8)));
typedef float floatx4 __attribute__((ext_vector_type(4)));

// ============ plan ============
// 1. y2[n][r*128+c] = feat[n] @ W[r]   (one MFMA GEMM [50k x 128] @ [128 x 1024], f16 out)
// 2. counting-sort edges by dst (50k bins) into records (base = src*1024+rel*128, w f16)
// 3. one wave per dst: out[d] = sum_e w_e * y2[base_e : base_e+128]   (no atomics)

#define NBINS3    N_NODES                         // 50000
#define NB3       ((NBINS3 + 1023) / 1024)        // 49

// ws layout (bytes)
#define WS_OFF    0                               // off  : NBINS3+1 i32 (200,004)
#define WS_BASE   200192                          // base : N_EDGES i32 (3,200,000)
#define WS_WGT    3400192                         // wgt  : N_EDGES f16 (1,600,000)
#define WS_WT     5000192                         // WT   : 1024 x 128 f16 (262,144)
#define WS_Y2     5262336                         // y2   : 50000 x 1024 f16 (102,400,000)
#define WS_HIST   WS_Y2                           // hist/cursors : 50000 i32 (aliased, dead before y2 written)
#define WS_BSUM   (WS_Y2 + 200000)                // bsum : NB3 i32
#define WS_NEED   (5262336 + (size_t)102400000)   // 107,662,336

// ---- sort: histogram over dst
__global__ void hist3_kernel(const int* __restrict__ dst, int* __restrict__ hist) {
    int i = blockIdx.x * blockDim.x + threadIdx.x;
    if (i < N_EDGES) atomicAdd(&hist[dst[i]], 1);
}

__global__ void scan1_kernel(const int* __restrict__ hist, int* __restrict__ bsum) {
    __shared__ int sh[256];
    int b = blockIdx.x, t = threadIdx.x;
    int i0 = b * 1024 + t * 4;
    int s = 0;
    #pragma unroll
    for (int j = 0; j < 4; j++) { int idx = i0 + j; if (idx < NBINS3) s += hist[idx]; }
    sh[t] = s; __syncthreads();
    for (int o = 128; o > 0; o >>= 1) { if (t < o) sh[t] += sh[t + o]; __syncthreads(); }
    if (t == 0) bsum[b] = sh[0];
}

__global__ void scan2_kernel(int* __restrict__ bsum, int* __restrict__ off) {
    if (threadIdx.x == 0 && blockIdx.x == 0) {
        int run = 0;
        for (int b = 0; b < NB3; b++) { int c = bsum[b]; bsum[b] = run; run += c; }
        off[NBINS3] = N_EDGES;
    }
}

__global__ void scan3_kernel(const int* __restrict__ hist, const int* __restrict__ boff,
                             int* __restrict__ off, int* __restrict__ cursors) {
    __shared__ int sh[256];
    int b = blockIdx.x, t = threadIdx.x;
    int i0 = b * 1024 + t * 4;
    int v[4]; int s = 0;
    #pragma unroll
    for (int j = 0; j < 4; j++) { int idx = i0 + j; v[j] = (idx < NBINS3) ? hist[idx] : 0; s += v[j]; }
    sh[t] = s; __syncthreads();
    for (int o = 1; o < 256; o <<= 1) {
        int x = (t >= o) ? sh[t - o] : 0;
        __syncthreads();
        sh[t] += x;
        __syncthreads();
    }
    int run = sh[t] - s + boff[b];
    #pragma unroll
    for (int j = 0; j < 4; j++) {
        int idx = i0 + j;
        if (idx < NBINS3) { off[idx] = run; cursors[idx] = run; }
        run += v[j];
    }
}

// scatter edge records: base = src*1024 + rel*128 (y2 row offset), w as f16
__global__ void scatter3_kernel(const int* __restrict__ dst, const int* __restrict__ src,
                                const int* __restrict__ rel, const float* __restrict__ ew,
                                int* __restrict__ cursors, int* __restrict__ base,
                                half_t* __restrict__ wgt) {
    int i = blockIdx.x * blockDim.x + threadIdx.x;
    if (i < N_EDGES) {
        int pos = atomicAdd(&cursors[dst[i]], 1);
        base[pos] = src[i] * 1024 + rel[i] * 128;
        wgt[pos] = (half_t)ew[i];
    }
}

// rel_emb [r][k][n] fp32  ->  WT [r*128+n][k] f16   (B^T for MFMA B-frag)
__global__ void prep_wt_kernel(const float* __restrict__ rel_emb, half_t* __restrict__ WT) {
    int t = blockIdx.x * blockDim.x + threadIdx.x;
    if (t < NUM_RELS * 128 * 128) {
        int r = t >> 14, k = (t >> 7) & 127, n = t & 127;
        WT[(size_t)((r << 7) | n) * 128 + k] = (half_t)rel_emb[t];
    }
}

// y2[50000 x 1024] = feat_f16[50000 x 128] @ WT^T ; tile M=128, N=128, K=128
#define APAD2 136   // half stride: 272B/row -> 4-bank advance/row -> 2-way (free)
__global__ __launch_bounds__(THREADS) void gemm_y_kernel(
    const float* __restrict__ feat, const half_t* __restrict__ WT,
    half_t* __restrict__ y2) {
    __shared__ half_t As[128][APAD2];   // 34.8 KB
    __shared__ half_t Bs[128][APAD2];   // 34.8 KB

    // XCD-swizzle: 3128 blocks = 8 xcds x 391 works; contiguous m-chunk per xcd
    int bid = blockIdx.x;
    int work = (bid & 7) * 391 + (bid >> 3);
    int mt = work >> 3, nt8 = work & 7;
    const int m0 = mt * 128, n0 = nt8 * 128;

    const int t = threadIdx.x;
    const int wave = t >> 6, lane = t & 63;
    const int q = lane >> 4, l16 = lane & 15;

    // stage A: feat f32 -> f16  (128 rows x 32 float4)
    for (int i = t; i < 128 * 32; i += THREADS) {
        int r = i >> 5, c4 = (i & 31) * 4;
        int row = m0 + r;
        float4 v = {0.f, 0.f, 0.f, 0.f};
        if (row < N_NODES) v = *(const float4*)(feat + (size_t)row * 128 + c4);
        half4v hv; hv[0] = (half_t)v.x; hv[1] = (half_t)v.y; hv[2] = (half_t)v.z; hv[3] = (half_t)v.w;
        *(half4v*)&As[r][c4] = hv;
    }
    // stage B: WT rows n0..n0+127  (128 rows x 16 uint4)
    for (int i = t; i < 128 * 16; i += THREADS) {
        int r = i >> 4, c = (i & 15) * 8;
        *(uint4*)&Bs[r][c] = *(const uint4*)(WT + (size_t)(n0 + r) * 128 + c);
    }
    __syncthreads();

    floatx4 acc[2][8];
    #pragma unroll
    for (int i = 0; i < 2; i++)
        #pragma unroll
        for (int j = 0; j < 8; j++) acc[i][j] = (floatx4){0.f, 0.f, 0.f, 0.f};

    #pragma unroll
    for (int ks = 0; ks < 128; ks += 32) {
        half8 a0 = *(const half8*)&As[wave * 32 + l16][ks + q * 8];
        half8 a1 = *(const half8*)&As[wave * 32 + 16 + l16][ks + q * 8];
        #pragma unroll
        for (int nt = 0; nt < 8; nt++) {
            half8 b = *(const half8*)&Bs[nt * 16 + l16][ks + q * 8];
            acc[0][nt] = __builtin_amdgcn_mfma_f32_16x16x32_f16(a0, b, acc[0][nt], 0, 0, 0);
            acc[1][nt] = __builtin_amdgcn_mfma_f32_16x16x32_f16(a1, b, acc[1][nt], 0, 0, 0);
        }
    }
    // C/D: col = l16, row = q*4 + reg
    #pragma unroll
    for (int rg = 0; rg < 2; rg++)
        #pragma unroll
        for (int nt = 0; nt < 8; nt++)
            #pragma unroll
            for (int reg = 0; reg < 4; reg++) {
                int row = m0 + wave * 32 + rg * 16 + q * 4 + reg;
                if (row < N_NODES)
                    y2[(size_t)row * 1024 + n0 + nt * 16 + l16] = (half_t)acc[rg][nt][reg];
            }
}

// one wave per dst: out[d][:] = sum_e w_e * y2[base_e : +128]
__global__ __launch_bounds__(THREADS) void gather_kernel(
    const half_t* __restrict__ y2, const int* __restrict__ base,
    const half_t* __restrict__ wgt, const int* __restrict__ off,
    float* __restrict__ out) {
    int g = blockIdx.x * 4 + (threadIdx.x >> 6);
    int lane = threadIdx.x & 63;
    int beg = off[g], end = off[g + 1];
    const half_t* yb = y2 + lane * 2;
    float ax = 0.f, ay = 0.f;
    int e = beg;
    for (; e + 4 <= end; e += 4) {
        int b0 = base[e], b1 = base[e + 1], b2 = base[e + 2], b3 = base[e + 3];
        half2v v0 = *(const half2v*)(yb + b0);
        half2v v1 = *(const half2v*)(yb + b1);
        half2v v2 = *(const half2v*)(yb + b2);
        half2v v3 = *(const half2v*)(yb + b3);
        float w0 = (float)wgt[e], w1 = (float)wgt[e + 1];
        float w2 = (float)wgt[e + 2], w3 = (float)wgt[e + 3];
        ax += w0 * (float)v0[0] + w1 * (float)v1[0] + w2 * (float)v2[0] + w3 * (float)v3[0];
        ay += w0 * (float)v0[1] + w1 * (float)v1[1] + w2 * (float)v2[1] + w3 * (float)v3[1];
    }
    for (; e < end; e++) {
        half2v v = *(const half2v*)(yb + base[e]);
        float w = (float)wgt[e];
        ax += w * (float)v[0];
        ay += w * (float)v[1];
    }
    float2 o; o.x = ax; o.y = ay;
    *(float2*)(out + (size_t)g * 128 + lane * 2) = o;
}

// ---- fallback (tiny ws): wave-per-edge direct with atomics
__global__ void naive_kernel(const float* __restrict__ feat, const float* __restrict__ rel_emb,
                             const float* __restrict__ ew, const int* __restrict__ src,
                             const int* __restrict__ dst, const int* __restrict__ rel,
                             float* __restrict__ out) {
    int wave = (blockIdx.x * blockDim.x + threadIdx.x) >> 6;
    int lane = threadIdx.x & 63;
    if (wave >= N_EDGES) return;
    const float* f = feat + (size_t)src[wave] * IN_DIM;
    const float* W = rel_emb + (size_t)rel[wave] * IN_DIM * OUT_DIM;
    float w = ew[wave];
    float a0 = 0.f, a1 = 0.f;
    for (int k = 0; k < IN_DIM; k++) {
        float fv = f[k];
        a0 += fv * W[k * OUT_DIM + lane];
        a1 += fv * W[k * OUT_DIM + 64 + lane];
    }
    int d = dst[wave];
    atomicAdd(&out[(size_t)d * OUT_DIM + lane], a0 * w);
    atomicAdd(&out[(size_t)d * OUT_DIM + 64 + lane], a1 * w);
}

extern "C" void kernel_launch(void* const* d_in, const int* in_sizes, int n_in,
                              void* d_out, int out_size, void* d_ws, size_t ws_size,
                              hipStream_t stream) {
    const float* feat    = (const float*)d_in[0];
    const float* rel_emb = (const float*)d_in[1];
    const float* ew      = (const float*)d_in[2];
    const int*   src     = (const int*)d_in[3];
    const int*   dst     = (const int*)d_in[4];
    const int*   rel     = (const int*)d_in[5];
    float* out = (float*)d_out;

    const int eb = (N_EDGES + THREADS - 1) / THREADS;   // 3125

    if (ws_size >= WS_NEED) {
        char* ws = (char*)d_ws;
        int*    off   = (int*)(ws + WS_OFF);
        int*    basep = (int*)(ws + WS_BASE);
        half_t* wgt   = (half_t*)(ws + WS_WGT);
        half_t* WT    = (half_t*)(ws + WS_WT);
        half_t* y2    = (half_t*)(ws + WS_Y2);
        int*    hist  = (int*)(ws + WS_HIST);   // aliased over y2 head (dead before y2 written)
        int*    bsum  = (int*)(ws + WS_BSUM);

        hipMemsetAsync(hist, 0, (size_t)NBINS3 * 4, stream);
        hist3_kernel<<<eb, THREADS, 0, stream>>>(dst, hist);
        scan1_kernel<<<NB3, 256, 0, stream>>>(hist, bsum);
        scan2_kernel<<<1, 64, 0, stream>>>(bsum, off);
        scan3_kernel<<<NB3, 256, 0, stream>>>(hist, bsum, off, hist);  // in-place -> cursors
        scatter3_kernel<<<eb, THREADS, 0, stream>>>(dst, src, rel, ew, hist, basep, wgt);
        prep_wt_kernel<<<(NUM_RELS * 128 * 128 + THREADS - 1) / THREADS, THREADS, 0, stream>>>(rel_emb, WT);
        gemm_y_kernel<<<391 * 8, THREADS, 0, stream>>>(feat, WT, y2);
        gather_kernel<<<N_NODES / 4, THREADS, 0, stream>>>(y2, basep, wgt, off, out);
    } else {
        hipMemsetAsync(d_out, 0, (size_t)out_size * sizeof(float), stream);
        const long long total = (long long)N_EDGES * 64;
        const int blocks = (int)((total + THREADS - 1) / THREADS);
        naive_kernel<<<blocks, THREADS, 0, stream>>>(feat, rel_emb, ew, src, dst, rel, out);
    }
}